// Round 1
// baseline (4532.030 us; speedup 1.0000x reference)
//
#include <hip/hip_runtime.h>
#include <math.h>

#define N_NODES 100000
#define N_EDGES 1600000
#define IN_FEATS 128
#define H_FEATS 64

// ---------------- degree (atomic histogram) ----------------
__global__ __launch_bounds__(256) void deg_kernel(const int* __restrict__ dst,
                                                  float* __restrict__ deg, int n_edges) {
    int tid = blockIdx.x * 256 + threadIdx.x;
    int stride = gridDim.x * 256;
    for (int e = tid; e < n_edges; e += stride)
        atomicAdd(&deg[dst[e]], 1.0f);
}

// deg -> d^{-1/2} in place
__global__ __launch_bounds__(256) void dinv_kernel(float* __restrict__ deg, int n) {
    int i = blockIdx.x * 256 + threadIdx.x;
    if (i < n) deg[i] = 1.0f / sqrtf(fmaxf(deg[i], 1.0f));
}

// ---------------- trunk: relu(relu(X@W1+b1)@W2+b2) ----------------
// block = 256 threads = 4 waves; wave-per-row; 8 row-iterations -> 32 rows/block.
// 3125 blocks * 32 = 100000 exactly (no tail).
__global__ __launch_bounds__(256) void trunk_kernel(
    const float* __restrict__ X, const float* __restrict__ W1, const float* __restrict__ b1,
    const float* __restrict__ W2, const float* __restrict__ b2, float* __restrict__ H)
{
    __shared__ float w1[IN_FEATS * H_FEATS];   // 32 KB, layout [i][j]
    __shared__ float w2[H_FEATS * H_FEATS];    // 16 KB
    __shared__ float xrow[4][IN_FEATS];
    __shared__ float h1row[4][H_FEATS];
    int t = threadIdx.x;
    for (int i = t; i < IN_FEATS * H_FEATS; i += 256) w1[i] = W1[i];
    for (int i = t; i < H_FEATS * H_FEATS; i += 256) w2[i] = W2[i];
    __syncthreads();
    int wave = t >> 6, lane = t & 63;
    float b1v = b1[lane], b2v = b2[lane];
    for (int it = 0; it < 8; ++it) {
        int row = blockIdx.x * 32 + it * 4 + wave;
        xrow[wave][lane]      = X[row * IN_FEATS + lane];
        xrow[wave][lane + 64] = X[row * IN_FEATS + 64 + lane];
        __syncthreads();
        float acc = b1v;
        #pragma unroll
        for (int i = 0; i < IN_FEATS; ++i)
            acc = fmaf(xrow[wave][i], w1[i * H_FEATS + lane], acc);
        h1row[wave][lane] = fmaxf(acc, 0.0f);
        __syncthreads();
        float acc2 = b2v;
        #pragma unroll
        for (int i = 0; i < H_FEATS; ++i)
            acc2 = fmaf(h1row[wave][i], w2[i * H_FEATS + lane], acc2);
        H[row * H_FEATS + lane] = fmaxf(acc2, 0.0f);
        __syncthreads();
    }
}

// ---------------- edge scatter: agg[dst] += feat[src] * dinv[src] ----------------
// work item = one float4 chunk of one edge (16 items/edge)
__global__ __launch_bounds__(256) void scatter_kernel(
    const float4* __restrict__ F4, const int* __restrict__ src, const int* __restrict__ dst,
    const float* __restrict__ dinv, float* __restrict__ agg)
{
    int tid = blockIdx.x * 256 + threadIdx.x;
    int stride = gridDim.x * 256;
    const int total = N_EDGES * 16;
    for (int w = tid; w < total; w += stride) {
        int e = w >> 4, c = w & 15;
        int s = src[e], d = dst[e];
        float wsc = dinv[s];
        float4 v = F4[(size_t)s * 16 + c];
        float* base = agg + (size_t)d * 64 + c * 4;
        atomicAdd(base + 0, v.x * wsc);
        atomicAdd(base + 1, v.y * wsc);
        atomicAdd(base + 2, v.z * wsc);
        atomicAdd(base + 3, v.w * wsc);
    }
}

// ---------------- Fnew = Fprev - agg*dinv[n];  agg re-zeroed for next pass ----------------
__global__ __launch_bounds__(256) void axpy_kernel(
    const float4* __restrict__ Fprev, float4* __restrict__ agg, float4* __restrict__ Fnew,
    const float* __restrict__ dinv)
{
    int idx = blockIdx.x * 256 + threadIdx.x;
    const int total = N_NODES * 16;
    if (idx >= total) return;
    int n = idx >> 4;
    float di = dinv[n];
    float4 a = agg[idx];
    agg[idx] = make_float4(0.f, 0.f, 0.f, 0.f);
    float4 p = Fprev[idx];
    float4 r;
    r.x = p.x - a.x * di;
    r.y = p.y - a.y * di;
    r.z = p.z - a.z * di;
    r.w = p.w - a.w * di;
    Fnew[idx] = r;
}

// ---------------- Weff[k][i][j] = sum_c thetas[c][k] * Wm1[c*64+i][j] ----------------
__global__ __launch_bounds__(256) void weff_kernel(const float* __restrict__ thetas,
                                                   const float* __restrict__ Wm1,
                                                   float* __restrict__ Weff) {
    int t = blockIdx.x * 256 + threadIdx.x;  // 16384 total
    int k = t >> 12, ij = t & 4095, i = ij >> 6, j = ij & 63;
    float acc = 0.f;
    #pragma unroll
    for (int c = 0; c < 3; ++c)
        acc = fmaf(thetas[c * 4 + k], Wm1[(c * 64 + i) * 64 + j], acc);
    Weff[t] = acc;
}

// ---------------- final: out = relu(sum_k Lk @ Weff[k] + bm1) @ Wm2 + bm2 ----------------
__global__ __launch_bounds__(256) void final_kernel(
    const float* __restrict__ L0, const float* __restrict__ L1,
    const float* __restrict__ L2, const float* __restrict__ L3,
    const float* __restrict__ Weff, const float* __restrict__ Wm2,
    const float* __restrict__ bm1, const float* __restrict__ bm2,
    float* __restrict__ out)
{
    __shared__ float weff[4 * 64 * 64];   // 64 KB
    __shared__ float wm2s[128];
    __shared__ float rowbuf[4][4][64];    // 4 KB
    int t = threadIdx.x;
    {
        const float4* s4 = (const float4*)Weff;
        float4* d4 = (float4*)weff;
        for (int i = t; i < 4 * 64 * 64 / 4; i += 256) d4[i] = s4[i];
    }
    if (t < 128) wm2s[t] = Wm2[t];
    __syncthreads();
    int wave = t >> 6, lane = t & 63;
    float b1v = bm1[lane];
    float bm20 = bm2[0], bm21 = bm2[1];
    const float* Ls[4] = {L0, L1, L2, L3};
    for (int r = 0; r < 8; ++r) {
        int row = blockIdx.x * 32 + wave * 8 + r;
        #pragma unroll
        for (int k = 0; k < 4; ++k)
            rowbuf[wave][k][lane] = Ls[k][(size_t)row * 64 + lane];
        __syncthreads();
        float acc = b1v;
        #pragma unroll
        for (int k = 0; k < 4; ++k)
            #pragma unroll
            for (int i = 0; i < 64; ++i)
                acc = fmaf(rowbuf[wave][k][i], weff[k * 4096 + i * 64 + lane], acc);
        acc = fmaxf(acc, 0.0f);
        float o0 = acc * wm2s[lane * 2 + 0];
        float o1 = acc * wm2s[lane * 2 + 1];
        #pragma unroll
        for (int off = 32; off > 0; off >>= 1) {
            o0 += __shfl_down(o0, off);
            o1 += __shfl_down(o1, off);
        }
        if (lane == 0) {
            out[row * 2 + 0] = o0 + bm20;
            out[row * 2 + 1] = o1 + bm21;
        }
        __syncthreads();
    }
}

extern "C" void kernel_launch(void* const* d_in, const int* in_sizes, int n_in,
                              void* d_out, int out_size, void* d_ws, size_t ws_size,
                              hipStream_t stream)
{
    const float* feature = (const float*)d_in[0];
    const int*   src     = (const int*)d_in[1];
    const int*   dst     = (const int*)d_in[2];
    const float* W1      = (const float*)d_in[3];
    const float* b1      = (const float*)d_in[4];
    const float* W2      = (const float*)d_in[5];
    const float* b2      = (const float*)d_in[6];
    const float* thetas  = (const float*)d_in[7];
    const float* Wm1     = (const float*)d_in[8];
    const float* bm1     = (const float*)d_in[9];
    const float* Wm2     = (const float*)d_in[10];
    const float* bm2     = (const float*)d_in[11];
    float* out = (float*)d_out;

    const size_t NH = (size_t)N_NODES * H_FEATS;  // 6.4M floats
    float* deg  = (float*)d_ws;          // N floats -> becomes dinv in place
    float* L0   = deg + 100352;          // 16B-aligned offsets
    float* L1   = L0 + NH;
    float* L2   = L1 + NH;
    float* L3   = L2 + NH;
    float* agg  = L3 + NH;
    float* Weff = agg + NH;              // 16384 floats
    // total ws use: ~128.5 MB

    hipMemsetAsync(deg, 0, N_NODES * sizeof(float), stream);
    hipMemsetAsync(agg, 0, NH * sizeof(float), stream);

    deg_kernel<<<2048, 256, 0, stream>>>(dst, deg, N_EDGES);
    dinv_kernel<<<(N_NODES + 255) / 256, 256, 0, stream>>>(deg, N_NODES);
    weff_kernel<<<64, 256, 0, stream>>>(thetas, Wm1, Weff);
    trunk_kernel<<<3125, 256, 0, stream>>>(feature, W1, b1, W2, b2, L0);

    float* Ls[4] = {L0, L1, L2, L3};
    for (int k = 1; k <= 3; ++k) {
        scatter_kernel<<<8192, 256, 0, stream>>>((const float4*)Ls[k - 1], src, dst, deg, agg);
        axpy_kernel<<<(N_NODES * 16 + 255) / 256, 256, 0, stream>>>(
            (const float4*)Ls[k - 1], (float4*)agg, (float4*)Ls[k], deg);
    }
    final_kernel<<<3125, 256, 0, stream>>>(L0, L1, L2, L3, Weff, Wm2, bm1, bm2, out);
}

// Round 2
// 723.154 us; speedup vs baseline: 6.2670x; 6.2670x over previous
//
#include <hip/hip_runtime.h>
#include <math.h>

#define N_NODES 100000
#define N_EDGES 1600000
#define IN_FEATS 128
#define H_FEATS 64
#define SCAN_BLOCKS 391   // ceil(100000/256)

// ---------------- int degree histogram ----------------
__global__ __launch_bounds__(256) void hist_kernel(const int* __restrict__ dst,
                                                   int* __restrict__ degi) {
    int tid = blockIdx.x * 256 + threadIdx.x;
    int stride = gridDim.x * 256;
    for (int e = tid; e < N_EDGES; e += stride)
        atomicAdd(&degi[dst[e]], 1);
}

// degi -> dinv = 1/sqrt(max(deg,1))
__global__ __launch_bounds__(256) void dinv_kernel(const int* __restrict__ degi,
                                                   float* __restrict__ dinv) {
    int i = blockIdx.x * 256 + threadIdx.x;
    if (i < N_NODES) dinv[i] = rsqrtf(fmaxf((float)degi[i], 1.0f));
}

// ---------------- 3-kernel exclusive scan of degi -> rowp ----------------
__global__ __launch_bounds__(256) void scan1_kernel(const int* __restrict__ degi,
                                                    int* __restrict__ rowp,
                                                    int* __restrict__ bsums) {
    __shared__ int tmp[256];
    int i = blockIdx.x * 256 + threadIdx.x;
    int v = (i < N_NODES) ? degi[i] : 0;
    tmp[threadIdx.x] = v;
    __syncthreads();
    #pragma unroll
    for (int off = 1; off < 256; off <<= 1) {
        int t = (threadIdx.x >= off) ? tmp[threadIdx.x - off] : 0;
        __syncthreads();
        tmp[threadIdx.x] += t;
        __syncthreads();
    }
    if (i < N_NODES) rowp[i] = tmp[threadIdx.x] - v;   // exclusive within block
    if (threadIdx.x == 255) bsums[blockIdx.x] = tmp[255];
}

__global__ __launch_bounds__(512) void scan2_kernel(int* __restrict__ bsums) {
    __shared__ int tmp[512];
    int t = threadIdx.x;
    int v = (t < SCAN_BLOCKS) ? bsums[t] : 0;
    tmp[t] = v;
    __syncthreads();
    #pragma unroll
    for (int off = 1; off < 512; off <<= 1) {
        int x = (t >= off) ? tmp[t - off] : 0;
        __syncthreads();
        tmp[t] += x;
        __syncthreads();
    }
    if (t < SCAN_BLOCKS) bsums[t] = tmp[t] - v;        // exclusive block offsets
}

__global__ __launch_bounds__(256) void scan3_kernel(int* __restrict__ rowp,
                                                    const int* __restrict__ bsums) {
    int i = blockIdx.x * 256 + threadIdx.x;
    if (i < N_NODES) rowp[i] += bsums[blockIdx.x];
    if (i == N_NODES) rowp[N_NODES] = N_EDGES;
}

// ---------------- fill CSR slots with src indices ----------------
__global__ __launch_bounds__(256) void fill_kernel(const int* __restrict__ src,
                                                   const int* __restrict__ dst,
                                                   const int* __restrict__ rowp,
                                                   int* __restrict__ cursor,
                                                   int* __restrict__ esrc) {
    int tid = blockIdx.x * 256 + threadIdx.x;
    int stride = gridDim.x * 256;
    for (int e = tid; e < N_EDGES; e += stride) {
        int d = dst[e];
        int slot = rowp[d] + atomicAdd(&cursor[d], 1);
        esrc[slot] = src[e];
    }
}

// ---------------- trunk: relu(relu(X@W1+b1)@W2+b2) ----------------
__global__ __launch_bounds__(256) void trunk_kernel(
    const float* __restrict__ X, const float* __restrict__ W1, const float* __restrict__ b1,
    const float* __restrict__ W2, const float* __restrict__ b2, float* __restrict__ H)
{
    __shared__ float w1[IN_FEATS * H_FEATS];   // 32 KB
    __shared__ float w2[H_FEATS * H_FEATS];    // 16 KB
    __shared__ float xrow[4][IN_FEATS];
    __shared__ float h1row[4][H_FEATS];
    int t = threadIdx.x;
    for (int i = t; i < IN_FEATS * H_FEATS; i += 256) w1[i] = W1[i];
    for (int i = t; i < H_FEATS * H_FEATS; i += 256) w2[i] = W2[i];
    __syncthreads();
    int wave = t >> 6, lane = t & 63;
    float b1v = b1[lane], b2v = b2[lane];
    for (int it = 0; it < 8; ++it) {
        int row = blockIdx.x * 32 + it * 4 + wave;
        xrow[wave][lane]      = X[row * IN_FEATS + lane];
        xrow[wave][lane + 64] = X[row * IN_FEATS + 64 + lane];
        __syncthreads();
        float acc = b1v;
        #pragma unroll
        for (int i = 0; i < IN_FEATS; ++i)
            acc = fmaf(xrow[wave][i], w1[i * H_FEATS + lane], acc);
        h1row[wave][lane] = fmaxf(acc, 0.0f);
        __syncthreads();
        float acc2 = b2v;
        #pragma unroll
        for (int i = 0; i < H_FEATS; ++i)
            acc2 = fmaf(h1row[wave][i], w2[i * H_FEATS + lane], acc2);
        H[row * H_FEATS + lane] = fmaxf(acc2, 0.0f);
        __syncthreads();
    }
}

// ---------------- gather pass: Fnew[n] = Fprev[n] - dinv[n]*sum_{e in in(n)} Fprev[src]*dinv[src]
// one wave per node, lane = feature dim
__global__ __launch_bounds__(256) void gather_kernel(
    const float* __restrict__ Fprev, const int* __restrict__ rowp,
    const int* __restrict__ esrc, const float* __restrict__ dinv,
    float* __restrict__ Fnew)
{
    int wid = blockIdx.x * 4 + (threadIdx.x >> 6);   // node id, grid covers exactly N
    int lane = threadIdx.x & 63;
    int beg = rowp[wid], end = rowp[wid + 1];
    float acc = 0.0f;
    int j = beg;
    for (; j + 3 < end; j += 4) {
        int s0 = esrc[j], s1 = esrc[j + 1], s2 = esrc[j + 2], s3 = esrc[j + 3];
        float w0 = dinv[s0], w1 = dinv[s1], w2 = dinv[s2], w3 = dinv[s3];
        float v0 = Fprev[(size_t)s0 * 64 + lane];
        float v1 = Fprev[(size_t)s1 * 64 + lane];
        float v2 = Fprev[(size_t)s2 * 64 + lane];
        float v3 = Fprev[(size_t)s3 * 64 + lane];
        acc = fmaf(v0, w0, acc);
        acc = fmaf(v1, w1, acc);
        acc = fmaf(v2, w2, acc);
        acc = fmaf(v3, w3, acc);
    }
    for (; j < end; ++j) {
        int s = esrc[j];
        acc = fmaf(Fprev[(size_t)s * 64 + lane], dinv[s], acc);
    }
    float di = dinv[wid];
    Fnew[(size_t)wid * 64 + lane] = Fprev[(size_t)wid * 64 + lane] - acc * di;
}

// ---------------- Weff[k][i][j] = sum_c thetas[c][k] * Wm1[c*64+i][j] ----------------
__global__ __launch_bounds__(256) void weff_kernel(const float* __restrict__ thetas,
                                                   const float* __restrict__ Wm1,
                                                   float* __restrict__ Weff) {
    int t = blockIdx.x * 256 + threadIdx.x;  // 16384 total
    int k = t >> 12, ij = t & 4095, i = ij >> 6, j = ij & 63;
    float acc = 0.f;
    #pragma unroll
    for (int c = 0; c < 3; ++c)
        acc = fmaf(thetas[c * 4 + k], Wm1[(c * 64 + i) * 64 + j], acc);
    Weff[t] = acc;
}

// ---------------- final: out = relu(sum_k Lk @ Weff[k] + bm1) @ Wm2 + bm2 ----------------
__global__ __launch_bounds__(256) void final_kernel(
    const float* __restrict__ L0, const float* __restrict__ L1,
    const float* __restrict__ L2, const float* __restrict__ L3,
    const float* __restrict__ Weff, const float* __restrict__ Wm2,
    const float* __restrict__ bm1, const float* __restrict__ bm2,
    float* __restrict__ out)
{
    __shared__ float weff[4 * 64 * 64];   // 64 KB
    __shared__ float wm2s[128];
    __shared__ float rowbuf[4][4][64];
    int t = threadIdx.x;
    {
        const float4* s4 = (const float4*)Weff;
        float4* d4 = (float4*)weff;
        for (int i = t; i < 4 * 64 * 64 / 4; i += 256) d4[i] = s4[i];
    }
    if (t < 128) wm2s[t] = Wm2[t];
    __syncthreads();
    int wave = t >> 6, lane = t & 63;
    float b1v = bm1[lane];
    float bm20 = bm2[0], bm21 = bm2[1];
    const float* Ls[4] = {L0, L1, L2, L3};
    for (int r = 0; r < 8; ++r) {
        int row = blockIdx.x * 32 + wave * 8 + r;
        #pragma unroll
        for (int k = 0; k < 4; ++k)
            rowbuf[wave][k][lane] = Ls[k][(size_t)row * 64 + lane];
        __syncthreads();
        float acc = b1v;
        #pragma unroll
        for (int k = 0; k < 4; ++k)
            #pragma unroll
            for (int i = 0; i < 64; ++i)
                acc = fmaf(rowbuf[wave][k][i], weff[k * 4096 + i * 64 + lane], acc);
        acc = fmaxf(acc, 0.0f);
        float o0 = acc * wm2s[lane * 2 + 0];
        float o1 = acc * wm2s[lane * 2 + 1];
        #pragma unroll
        for (int off = 32; off > 0; off >>= 1) {
            o0 += __shfl_down(o0, off);
            o1 += __shfl_down(o1, off);
        }
        if (lane == 0) {
            out[row * 2 + 0] = o0 + bm20;
            out[row * 2 + 1] = o1 + bm21;
        }
        __syncthreads();
    }
}

extern "C" void kernel_launch(void* const* d_in, const int* in_sizes, int n_in,
                              void* d_out, int out_size, void* d_ws, size_t ws_size,
                              hipStream_t stream)
{
    const float* feature = (const float*)d_in[0];
    const int*   src     = (const int*)d_in[1];
    const int*   dst     = (const int*)d_in[2];
    const float* W1      = (const float*)d_in[3];
    const float* b1      = (const float*)d_in[4];
    const float* W2      = (const float*)d_in[5];
    const float* b2      = (const float*)d_in[6];
    const float* thetas  = (const float*)d_in[7];
    const float* Wm1     = (const float*)d_in[8];
    const float* bm1     = (const float*)d_in[9];
    const float* Wm2     = (const float*)d_in[10];
    const float* bm2     = (const float*)d_in[11];
    float* out = (float*)d_out;

    const size_t NH = (size_t)N_NODES * H_FEATS;   // 6.4M floats
    const int NPAD = 100352;                        // N rounded up, 16B-aligned elems
    float* dinv   = (float*)d_ws;                   // N floats
    int*   degi   = (int*)(dinv + NPAD);            // N ints
    int*   rowp   = degi + NPAD;                    // N+1 ints
    int*   bsums  = rowp + NPAD;                    // 512 ints
    int*   cursor = bsums + 512;                    // N ints
    int*   esrc   = cursor + NPAD;                  // E ints
    float* L0     = (float*)(esrc + N_EDGES);
    float* L1     = L0 + NH;
    float* L2     = L1 + NH;
    float* L3     = L2 + NH;
    float* Weff   = L3 + NH;                        // 16384 floats
    // total ws use ≈ 110 MB

    hipMemsetAsync(degi,   0, N_NODES * sizeof(int), stream);
    hipMemsetAsync(cursor, 0, N_NODES * sizeof(int), stream);

    hist_kernel<<<1024, 256, 0, stream>>>(dst, degi);
    dinv_kernel<<<(N_NODES + 255) / 256, 256, 0, stream>>>(degi, dinv);
    scan1_kernel<<<SCAN_BLOCKS, 256, 0, stream>>>(degi, rowp, bsums);
    scan2_kernel<<<1, 512, 0, stream>>>(bsums);
    scan3_kernel<<<SCAN_BLOCKS, 256, 0, stream>>>(rowp, bsums);
    fill_kernel<<<1024, 256, 0, stream>>>(src, dst, rowp, cursor, esrc);

    weff_kernel<<<64, 256, 0, stream>>>(thetas, Wm1, Weff);
    trunk_kernel<<<3125, 256, 0, stream>>>(feature, W1, b1, W2, b2, L0);

    float* Ls[4] = {L0, L1, L2, L3};
    for (int k = 1; k <= 3; ++k)
        gather_kernel<<<25000, 256, 0, stream>>>(Ls[k - 1], rowp, esrc, dinv, Ls[k]);

    final_kernel<<<3125, 256, 0, stream>>>(L0, L1, L2, L3, Weff, Wm2, bm1, bm2, out);
}

// Round 3
// 557.395 us; speedup vs baseline: 8.1307x; 1.2974x over previous
//
#include <hip/hip_runtime.h>
#include <math.h>

#define N_NODES 100000
#define N_EDGES 1600000
#define IN_FEATS 128
#define H_FEATS 64
#define SCAN_BLOCKS 391   // ceil(100000/256)

// ---------------- int degree histogram ----------------
__global__ __launch_bounds__(256) void hist_kernel(const int* __restrict__ dst,
                                                   int* __restrict__ degi) {
    int tid = blockIdx.x * 256 + threadIdx.x;
    int stride = gridDim.x * 256;
    for (int e = tid; e < N_EDGES; e += stride)
        atomicAdd(&degi[dst[e]], 1);
}

// degi -> dinv = 1/sqrt(max(deg,1))
__global__ __launch_bounds__(256) void dinv_kernel(const int* __restrict__ degi,
                                                   float* __restrict__ dinv) {
    int i = blockIdx.x * 256 + threadIdx.x;
    if (i < N_NODES) dinv[i] = rsqrtf(fmaxf((float)degi[i], 1.0f));
}

// ---------------- 3-kernel exclusive scan of degi -> rowp ----------------
__global__ __launch_bounds__(256) void scan1_kernel(const int* __restrict__ degi,
                                                    int* __restrict__ rowp,
                                                    int* __restrict__ bsums) {
    __shared__ int tmp[256];
    int i = blockIdx.x * 256 + threadIdx.x;
    int v = (i < N_NODES) ? degi[i] : 0;
    tmp[threadIdx.x] = v;
    __syncthreads();
    #pragma unroll
    for (int off = 1; off < 256; off <<= 1) {
        int t = (threadIdx.x >= off) ? tmp[threadIdx.x - off] : 0;
        __syncthreads();
        tmp[threadIdx.x] += t;
        __syncthreads();
    }
    if (i < N_NODES) rowp[i] = tmp[threadIdx.x] - v;   // exclusive within block
    if (threadIdx.x == 255) bsums[blockIdx.x] = tmp[255];
}

__global__ __launch_bounds__(512) void scan2_kernel(int* __restrict__ bsums) {
    __shared__ int tmp[512];
    int t = threadIdx.x;
    int v = (t < SCAN_BLOCKS) ? bsums[t] : 0;
    tmp[t] = v;
    __syncthreads();
    #pragma unroll
    for (int off = 1; off < 512; off <<= 1) {
        int x = (t >= off) ? tmp[t - off] : 0;
        __syncthreads();
        tmp[t] += x;
        __syncthreads();
    }
    if (t < SCAN_BLOCKS) bsums[t] = tmp[t] - v;        // exclusive block offsets
}

__global__ __launch_bounds__(256) void scan3_kernel(int* __restrict__ rowp,
                                                    const int* __restrict__ bsums) {
    int i = blockIdx.x * 256 + threadIdx.x;
    if (i < N_NODES) rowp[i] += bsums[blockIdx.x];
    if (i == N_NODES) rowp[N_NODES] = N_EDGES;
}

// ---------------- fill CSR slots with src indices ----------------
__global__ __launch_bounds__(256) void fill_kernel(const int* __restrict__ src,
                                                   const int* __restrict__ dst,
                                                   const int* __restrict__ rowp,
                                                   int* __restrict__ cursor,
                                                   int* __restrict__ esrc) {
    int tid = blockIdx.x * 256 + threadIdx.x;
    int stride = gridDim.x * 256;
    for (int e = tid; e < N_EDGES; e += stride) {
        int d = dst[e];
        int slot = rowp[d] + atomicAdd(&cursor[d], 1);
        esrc[slot] = src[e];
    }
}

// ---------------- trunk: relu(relu(X@W1+b1)@W2+b2) ----------------
// K split across 4 waves; weights in VGPRs; row activations via scalar loads.
__global__ __launch_bounds__(256) void trunk_kernel(
    const float* __restrict__ X, const float* __restrict__ W1, const float* __restrict__ b1,
    const float* __restrict__ W2, const float* __restrict__ b2, float* __restrict__ H)
{
    __shared__ float part[4][4][64];   // [wave][r][lane] partials
    __shared__ float h1[4][64];        // relu'd layer-1 rows
    int t = threadIdx.x;
    int wv = __builtin_amdgcn_readfirstlane(t >> 6);   // wave id, SGPR-uniform
    int lane = t & 63;
    float w1r[32], w2r[16];
    #pragma unroll
    for (int i = 0; i < 32; ++i) w1r[i] = W1[(wv * 32 + i) * 64 + lane];
    #pragma unroll
    for (int i = 0; i < 16; ++i) w2r[i] = W2[(wv * 16 + i) * 64 + lane];
    float b1v = b1[lane], b2v = b2[lane];
    for (int batch = 0; batch < 8; ++batch) {
        int row0 = blockIdx.x * 32 + batch * 4;
        float acc[4] = {0.f, 0.f, 0.f, 0.f};
        #pragma unroll
        for (int r = 0; r < 4; ++r) {
            const float* xr = X + (size_t)(row0 + r) * IN_FEATS + wv * 32;  // uniform addr
            #pragma unroll
            for (int i = 0; i < 32; ++i)
                acc[r] = fmaf(xr[i], w1r[i], acc[r]);
        }
        #pragma unroll
        for (int r = 0; r < 4; ++r) part[wv][r][lane] = acc[r];
        __syncthreads();
        // wave wv reduces row (row0+wv)
        float y1 = part[0][wv][lane] + part[1][wv][lane] +
                   part[2][wv][lane] + part[3][wv][lane] + b1v;
        h1[wv][lane] = fmaxf(y1, 0.f);
        __syncthreads();
        float acc2[4] = {0.f, 0.f, 0.f, 0.f};
        #pragma unroll
        for (int i = 0; i < 16; ++i) {
            #pragma unroll
            for (int r = 0; r < 4; ++r)
                acc2[r] = fmaf(h1[r][wv * 16 + i], w2r[i], acc2[r]);  // broadcast LDS read
        }
        __syncthreads();   // done reading part from layer 1
        #pragma unroll
        for (int r = 0; r < 4; ++r) part[wv][r][lane] = acc2[r];
        __syncthreads();
        float y2 = part[0][wv][lane] + part[1][wv][lane] +
                   part[2][wv][lane] + part[3][wv][lane] + b2v;
        H[(size_t)(row0 + wv) * 64 + lane] = fmaxf(y2, 0.f);
        __syncthreads();   // before next batch overwrites part/h1
    }
}

// ---------------- gather pass: Fnew[n] = Fprev[n] - dinv[n]*sum_{src in in(n)} Fprev[src]*dinv[src]
// one wave per node, lane = feature dim; 8 row-loads in flight
__global__ __launch_bounds__(256) void gather_kernel(
    const float* __restrict__ Fprev, const int* __restrict__ rowp,
    const int* __restrict__ esrc, const float* __restrict__ dinv,
    float* __restrict__ Fnew)
{
    int wv = __builtin_amdgcn_readfirstlane(threadIdx.x >> 6);
    int wid = blockIdx.x * 4 + wv;   // node id (uniform)
    int lane = threadIdx.x & 63;
    int beg = rowp[wid], end = rowp[wid + 1];
    float acc = 0.0f;
    int j = beg;
    for (; j + 7 < end; j += 8) {
        int s0 = esrc[j],     s1 = esrc[j + 1], s2 = esrc[j + 2], s3 = esrc[j + 3];
        int s4 = esrc[j + 4], s5 = esrc[j + 5], s6 = esrc[j + 6], s7 = esrc[j + 7];
        float v0 = Fprev[(size_t)s0 * 64 + lane];
        float v1 = Fprev[(size_t)s1 * 64 + lane];
        float v2 = Fprev[(size_t)s2 * 64 + lane];
        float v3 = Fprev[(size_t)s3 * 64 + lane];
        float v4 = Fprev[(size_t)s4 * 64 + lane];
        float v5 = Fprev[(size_t)s5 * 64 + lane];
        float v6 = Fprev[(size_t)s6 * 64 + lane];
        float v7 = Fprev[(size_t)s7 * 64 + lane];
        acc = fmaf(v0, dinv[s0], acc);
        acc = fmaf(v1, dinv[s1], acc);
        acc = fmaf(v2, dinv[s2], acc);
        acc = fmaf(v3, dinv[s3], acc);
        acc = fmaf(v4, dinv[s4], acc);
        acc = fmaf(v5, dinv[s5], acc);
        acc = fmaf(v6, dinv[s6], acc);
        acc = fmaf(v7, dinv[s7], acc);
    }
    for (; j < end; ++j) {
        int s = esrc[j];
        acc = fmaf(Fprev[(size_t)s * 64 + lane], dinv[s], acc);
    }
    float di = dinv[wid];
    Fnew[(size_t)wid * 64 + lane] = Fprev[(size_t)wid * 64 + lane] - acc * di;
}

// ---------------- Weff[k][i][j] = sum_c thetas[c][k] * Wm1[c*64+i][j] ----------------
__global__ __launch_bounds__(256) void weff_kernel(const float* __restrict__ thetas,
                                                   const float* __restrict__ Wm1,
                                                   float* __restrict__ Weff) {
    int t = blockIdx.x * 256 + threadIdx.x;  // 16384 total
    int k = t >> 12, ij = t & 4095, i = ij >> 6, j = ij & 63;
    float acc = 0.f;
    #pragma unroll
    for (int c = 0; c < 3; ++c)
        acc = fmaf(thetas[c * 4 + k], Wm1[(c * 64 + i) * 64 + j], acc);
    Weff[t] = acc;
}

// ---------------- final: out = relu(sum_k Lk @ Weff[k] + bm1) @ Wm2 + bm2 ----------------
// wave wv handles K-block k=wv (matrix L_wv, Weff[wv]) with weights in 64 VGPRs.
__global__ __launch_bounds__(256) void final_kernel(
    const float* __restrict__ L0, const float* __restrict__ L1,
    const float* __restrict__ L2, const float* __restrict__ L3,
    const float* __restrict__ Weff, const float* __restrict__ Wm2,
    const float* __restrict__ bm1, const float* __restrict__ bm2,
    float* __restrict__ out)
{
    __shared__ float part[4][4][64];   // [wave][r][lane]
    __shared__ float wm2s[128];
    int t = threadIdx.x;
    int wv = __builtin_amdgcn_readfirstlane(t >> 6);
    int lane = t & 63;
    float wreg[64];
    #pragma unroll
    for (int i = 0; i < 64; ++i)
        wreg[i] = Weff[wv * 4096 + i * 64 + lane];
    if (t < 128) wm2s[t] = Wm2[t];
    float b1v = bm1[lane];
    float bm20 = bm2[0], bm21 = bm2[1];
    const float* Lw = (wv == 0) ? L0 : (wv == 1) ? L1 : (wv == 2) ? L2 : L3;
    __syncthreads();
    for (int batch = 0; batch < 8; ++batch) {
        int row0 = blockIdx.x * 32 + batch * 4;
        float acc[4] = {0.f, 0.f, 0.f, 0.f};
        #pragma unroll
        for (int r = 0; r < 4; ++r) {
            const float* xr = Lw + (size_t)(row0 + r) * 64;   // uniform addr -> s_load
            #pragma unroll
            for (int i = 0; i < 64; ++i)
                acc[r] = fmaf(xr[i], wreg[i], acc[r]);
        }
        #pragma unroll
        for (int r = 0; r < 4; ++r) part[wv][r][lane] = acc[r];
        __syncthreads();
        // wave wv finishes row (row0+wv): reduce K-partials, relu, head GEMV
        float y = part[0][wv][lane] + part[1][wv][lane] +
                  part[2][wv][lane] + part[3][wv][lane] + b1v;
        y = fmaxf(y, 0.f);
        float o0 = y * wm2s[lane * 2 + 0];
        float o1 = y * wm2s[lane * 2 + 1];
        #pragma unroll
        for (int off = 32; off > 0; off >>= 1) {
            o0 += __shfl_down(o0, off);
            o1 += __shfl_down(o1, off);
        }
        if (lane == 0) {
            out[(row0 + wv) * 2 + 0] = o0 + bm20;
            out[(row0 + wv) * 2 + 1] = o1 + bm21;
        }
        __syncthreads();
    }
}

extern "C" void kernel_launch(void* const* d_in, const int* in_sizes, int n_in,
                              void* d_out, int out_size, void* d_ws, size_t ws_size,
                              hipStream_t stream)
{
    const float* feature = (const float*)d_in[0];
    const int*   src     = (const int*)d_in[1];
    const int*   dst     = (const int*)d_in[2];
    const float* W1      = (const float*)d_in[3];
    const float* b1      = (const float*)d_in[4];
    const float* W2      = (const float*)d_in[5];
    const float* b2      = (const float*)d_in[6];
    const float* thetas  = (const float*)d_in[7];
    const float* Wm1     = (const float*)d_in[8];
    const float* bm1     = (const float*)d_in[9];
    const float* Wm2     = (const float*)d_in[10];
    const float* bm2     = (const float*)d_in[11];
    float* out = (float*)d_out;

    const size_t NH = (size_t)N_NODES * H_FEATS;   // 6.4M floats
    const int NPAD = 100352;                        // N rounded up, 16B-aligned elems
    float* dinv   = (float*)d_ws;                   // N floats
    int*   degi   = (int*)(dinv + NPAD);            // N ints
    int*   rowp   = degi + NPAD;                    // N+1 ints
    int*   bsums  = rowp + NPAD;                    // 512 ints
    int*   cursor = bsums + 512;                    // N ints
    int*   esrc   = cursor + NPAD;                  // E ints
    float* L0     = (float*)(esrc + N_EDGES);
    float* L1     = L0 + NH;
    float* L2     = L1 + NH;
    float* L3     = L2 + NH;
    float* Weff   = L3 + NH;                        // 16384 floats
    // total ws use ≈ 110 MB

    hipMemsetAsync(degi,   0, N_NODES * sizeof(int), stream);
    hipMemsetAsync(cursor, 0, N_NODES * sizeof(int), stream);

    hist_kernel<<<1024, 256, 0, stream>>>(dst, degi);
    dinv_kernel<<<(N_NODES + 255) / 256, 256, 0, stream>>>(degi, dinv);
    scan1_kernel<<<SCAN_BLOCKS, 256, 0, stream>>>(degi, rowp, bsums);
    scan2_kernel<<<1, 512, 0, stream>>>(bsums);
    scan3_kernel<<<SCAN_BLOCKS, 256, 0, stream>>>(rowp, bsums);
    fill_kernel<<<1024, 256, 0, stream>>>(src, dst, rowp, cursor, esrc);

    weff_kernel<<<64, 256, 0, stream>>>(thetas, Wm1, Weff);
    trunk_kernel<<<3125, 256, 0, stream>>>(feature, W1, b1, W2, b2, L0);

    float* Ls[4] = {L0, L1, L2, L3};
    for (int k = 1; k <= 3; ++k)
        gather_kernel<<<25000, 256, 0, stream>>>(Ls[k - 1], rowp, esrc, dinv, Ls[k]);

    final_kernel<<<3125, 256, 0, stream>>>(L0, L1, L2, L3, Weff, Wm2, bm1, bm2, out);
}